// Round 14
// baseline (302.185 us; speedup 1.0000x reference)
//
#include <hip/hip_runtime.h>
#include <hip/hip_bf16.h>
#include <math.h>

#define NN   4096
#define EE   131072
#define HH   4
#define DIN  128
#define DH   256
#define DCAT 1024   /* HH*DH */
#define ALPHA_LR 0.2f
#define MAXDEG 256

typedef __attribute__((ext_vector_type(8))) short  short8;
typedef __attribute__((ext_vector_type(4))) short  s16x4;
typedef __attribute__((ext_vector_type(4))) float  f32x4;

__device__ __forceinline__ unsigned short f2bf(float f) {
    union { float f; unsigned u; } v; v.f = f;
    unsigned r = v.u + 0x7fffu + ((v.u >> 16) & 1u);
    return (unsigned short)(r >> 16);
}
__device__ __forceinline__ float bf2f(unsigned short us) {
    union { unsigned u; float f; } v; v.u = ((unsigned)us) << 16;
    return v.f;
}

// ------------------------------------------------------------------
// merged prep: cast x -> bf16 | 4 weight transposes | edge counts
// ------------------------------------------------------------------
__global__ void prep_kernel(const float* __restrict__ x, unsigned short* __restrict__ xb,
                            const float* __restrict__ Wp, unsigned short* __restrict__ BTp,
                            const float* __restrict__ W0, unsigned short* __restrict__ BT0,
                            const float* __restrict__ W1, unsigned short* __restrict__ BT1,
                            const float* __restrict__ W2, unsigned short* __restrict__ BT2,
                            const int* __restrict__ src, const int* __restrict__ dst,
                            int* __restrict__ counts, int* __restrict__ counts2)
{
    __shared__ float tile[32][33];
    const int b = blockIdx.x, tid = threadIdx.x;
    if (b < 512) {                               // cast x
        int i = b * 256 + tid;
        f32x4 v = *(const f32x4*)(x + (size_t)i * 4);
        s16x4 o;
        o[0] = (short)f2bf(v[0]); o[1] = (short)f2bf(v[1]);
        o[2] = (short)f2bf(v[2]); o[3] = (short)f2bf(v[3]);
        *(s16x4*)(xb + (size_t)i * 4) = o;
        return;
    }
    if (b >= 2848) {                             // edge degree counts
        int e = (b - 2848) * 256 + tid;
        atomicAdd(&counts[src[e]], 1);
        atomicAdd(&counts2[dst[e]], 1);
        return;
    }
    const float* W; unsigned short* BT; int K, h, kt, ot;
    if (b < 544)       { int c = b - 512;  W = Wp; BT = BTp; K = DIN;  h = 0;      kt = c & 3;  ot = c >> 2; }
    else if (b < 800)  { int c = b - 544;  W = W0; BT = BT0; K = DH;   h = c >> 6; kt = c & 7;  ot = (c >> 3) & 7; }
    else if (b < 1824) { int c = b - 800;  W = W1; BT = BT1; K = DCAT; h = c >> 8; kt = c & 31; ot = (c >> 5) & 7; }
    else               { int c = b - 1824; W = W2; BT = BT2; K = DCAT; h = c >> 8; kt = c & 31; ot = (c >> 5) & 7; }
    int k0 = kt * 32, o0 = ot * 32;
    int tx = tid & 31, ty = tid >> 5;
    const float* Ws = W + (size_t)h * K * 256;
#pragma unroll
    for (int i = 0; i < 32; i += 8)
        tile[ty + i][tx] = Ws[(size_t)(k0 + ty + i) * 256 + o0 + tx];
    __syncthreads();
#pragma unroll
    for (int i = 0; i < 32; i += 8)
        BT[(size_t)(h * 256 + o0 + ty + i) * K + k0 + tx] = f2bf(tile[tx][ty + i]);
}

// ------------------------------------------------------------------
// bf16 MFMA GEMM; head_major writes C as [h][N][256] (for Whb).
// Fused es/ed/csum epilogue when av != null.
// ------------------------------------------------------------------
__global__ __launch_bounds__(256)
void mfma_gemm_kernel(const unsigned short* __restrict__ A,
                      const unsigned short* __restrict__ BT,
                      int K,
                      unsigned short* __restrict__ Cb,
                      int ldc, int head_major,
                      const float* __restrict__ bias, int relu_act,
                      const float* __restrict__ av,
                      float* __restrict__ es4, float* __restrict__ ed4,
                      float* __restrict__ csum)
{
    __shared__ __align__(16) unsigned short sA[2][128 * 32];
    __shared__ __align__(16) unsigned short sB[2][128 * 32];

    const int tid = threadIdx.x;
    const int w = tid >> 6, l = tid & 63;
    const int wr = w >> 1, wc = w & 1;
    const int row0 = blockIdx.x * 128, col0 = blockIdx.y * 128;
    const int lrow = l >> 2;
    const int lce  = (l & 3) * 8;
    const int lr = l & 15, lg = l >> 4;

    f32x4 acc[4][4];
#pragma unroll
    for (int m = 0; m < 4; ++m)
#pragma unroll
        for (int n = 0; n < 4; ++n)
            acc[m][n] = (f32x4){0.f, 0.f, 0.f, 0.f};

#define STAGE(buf, k0)                                                          \
    {                                                                           \
        _Pragma("unroll")                                                       \
        for (int p = 0; p < 2; ++p) {                                           \
            int chunk = w * 2 + p;                                              \
            int r = chunk * 16 + lrow;                                          \
            const unsigned short* ga = A  + (size_t)(row0 + r) * K + (k0) + lce;\
            const unsigned short* gb = BT + (size_t)(col0 + r) * K + (k0) + lce;\
            __builtin_amdgcn_global_load_lds(                                   \
                (const __attribute__((address_space(1))) unsigned int*)ga,      \
                (__attribute__((address_space(3))) unsigned int*)(&sA[buf][chunk * 512]), \
                16, 0, 0);                                                      \
            __builtin_amdgcn_global_load_lds(                                   \
                (const __attribute__((address_space(1))) unsigned int*)gb,      \
                (__attribute__((address_space(3))) unsigned int*)(&sB[buf][chunk * 512]), \
                16, 0, 0);                                                      \
        }                                                                       \
    }

#define COMPUTE(buf)                                                            \
    {                                                                           \
        short8 af[4], bfr[4];                                                   \
        _Pragma("unroll")                                                       \
        for (int m = 0; m < 4; ++m) {                                           \
            int r = wr * 64 + m * 16 + lr;                                      \
            af[m] = *(const short8*)(&sA[buf][r * 32 + lg * 8]);                \
        }                                                                       \
        _Pragma("unroll")                                                       \
        for (int n = 0; n < 4; ++n) {                                           \
            int r = wc * 64 + n * 16 + lr;                                      \
            bfr[n] = *(const short8*)(&sB[buf][r * 32 + lg * 8]);               \
        }                                                                       \
        _Pragma("unroll")                                                       \
        for (int m = 0; m < 4; ++m)                                             \
            _Pragma("unroll")                                                   \
            for (int n = 0; n < 4; ++n)                                         \
                acc[m][n] = __builtin_amdgcn_mfma_f32_16x16x32_bf16(            \
                    af[m], bfr[n], acc[m][n], 0, 0, 0);                         \
    }

    STAGE(0, 0);
    __syncthreads();
    int nt = K >> 5, cur = 0;
    for (int t = 0; t < nt - 1; ++t) {
        STAGE(cur ^ 1, (t + 1) * 32);
        COMPUTE(cur);
        __syncthreads();
        cur ^= 1;
    }
    COMPUTE(cur);
#undef STAGE
#undef COMPUTE

    // C-write
#pragma unroll
    for (int m = 0; m < 4; ++m) {
        int rbase = row0 + wr * 64 + m * 16 + lg * 4;
#pragma unroll
        for (int n = 0; n < 4; ++n) {
            int c = col0 + wc * 64 + n * 16 + lr;
            float bv = bias ? bias[c] : 0.f;
#pragma unroll
            for (int r = 0; r < 4; ++r) {
                float v = acc[m][n][r] + bv;
                if (relu_act) v = fmaxf(v, 0.f);
                size_t idx = head_major
                    ? (size_t)(c >> 8) * ((size_t)NN * DH) + (size_t)(rbase + r) * DH + (c & 255)
                    : (size_t)(rbase + r) * ldc + c;
                Cb[idx] = f2bf(v);
            }
        }
    }

    // fused attvec + colsum epilogue
    if (av) {
        const int h = (col0 + wc * 64) >> 8;
        float aes[4], aed[4];
#pragma unroll
        for (int n = 0; n < 4; ++n) {
            int cc = (col0 + wc * 64 + n * 16 + lr) & 255;
            aes[n] = av[h * 2 * DH + cc];
            aed[n] = av[h * 2 * DH + DH + cc];
        }
#pragma unroll
        for (int m = 0; m < 4; ++m) {
#pragma unroll
            for (int r = 0; r < 4; ++r) {
                float se = 0.f, sd = 0.f;
#pragma unroll
                for (int n = 0; n < 4; ++n) {
                    se = fmaf(aes[n], acc[m][n][r], se);
                    sd = fmaf(aed[n], acc[m][n][r], sd);
                }
                se += __shfl_xor(se, 1);  sd += __shfl_xor(sd, 1);
                se += __shfl_xor(se, 2);  sd += __shfl_xor(sd, 2);
                se += __shfl_xor(se, 4);  sd += __shfl_xor(sd, 4);
                se += __shfl_xor(se, 8);  sd += __shfl_xor(sd, 8);
                if (lr == 0) {
                    int row = row0 + wr * 64 + m * 16 + lg * 4 + r;
                    atomicAdd(&es4[row * 4 + h], se);
                    atomicAdd(&ed4[row * 4 + h], sd);
                }
            }
        }
#pragma unroll
        for (int n = 0; n < 4; ++n) {
            float s = 0.f;
#pragma unroll
            for (int m = 0; m < 4; ++m)
#pragma unroll
                for (int r = 0; r < 4; ++r)
                    s += acc[m][n][r];
            s += __shfl_xor(s, 16);
            s += __shfl_xor(s, 32);
            if (lg == 0) atomicAdd(&csum[col0 + wc * 64 + n * 16 + lr], s);
        }
    }
}

// ------------------------------------------------------------------
// dual scan + fill (CSR/CSC)
// ------------------------------------------------------------------
__global__ void scan2_kernel(const int* __restrict__ countsA, const int* __restrict__ countsB,
                             int* __restrict__ rowptr, int* __restrict__ cursor,
                             int* __restrict__ cscptr, int* __restrict__ ccursor)
{
    __shared__ int lsumA[1024];
    __shared__ int lsumB[1024];
    int t = threadIdx.x;
    int base = t * 4;
    int a0 = countsA[base], a1 = countsA[base + 1], a2 = countsA[base + 2], a3 = countsA[base + 3];
    int b0 = countsB[base], b1 = countsB[base + 1], b2 = countsB[base + 2], b3 = countsB[base + 3];
    int sA = a0 + a1 + a2 + a3;
    int sB = b0 + b1 + b2 + b3;
    lsumA[t] = sA; lsumB[t] = sB;
    __syncthreads();
    for (int off = 1; off < 1024; off <<= 1) {
        int vA = (t >= off) ? lsumA[t - off] : 0;
        int vB = (t >= off) ? lsumB[t - off] : 0;
        __syncthreads();
        lsumA[t] += vA; lsumB[t] += vB;
        __syncthreads();
    }
    int eA = lsumA[t] - sA;
    rowptr[base] = eA;               cursor[base] = eA;
    rowptr[base + 1] = eA + a0;      cursor[base + 1] = eA + a0;
    rowptr[base + 2] = eA + a0 + a1; cursor[base + 2] = eA + a0 + a1;
    rowptr[base + 3] = eA + a0 + a1 + a2; cursor[base + 3] = eA + a0 + a1 + a2;
    int eB = lsumB[t] - sB;
    cscptr[base] = eB;               ccursor[base] = eB;
    cscptr[base + 1] = eB + b0;      ccursor[base + 1] = eB + b0;
    cscptr[base + 2] = eB + b0 + b1; ccursor[base + 2] = eB + b0 + b1;
    cscptr[base + 3] = eB + b0 + b1 + b2; ccursor[base + 3] = eB + b0 + b1 + b2;
    if (t == 1023) { rowptr[NN] = lsumA[1023]; cscptr[NN] = lsumB[1023]; }
}

__global__ void fill_kernel(const int* __restrict__ src, const int* __restrict__ dst,
                            int* __restrict__ cursor, int* __restrict__ ccursor,
                            int* __restrict__ cdst, int* __restrict__ cscpos)
{
    int e = blockIdx.x * 256 + threadIdx.x;
    int s = src[e], d = dst[e];
    int pos = atomicAdd(&cursor[s], 1);
    cdst[pos] = d;
    int cp = atomicAdd(&ccursor[d], 1);
    cscpos[cp] = pos;
}

// ------------------------------------------------------------------
// Ctot = sum of invd4_3 (few atomics)
// ------------------------------------------------------------------
__global__ void ctot_reduce_kernel(const float* __restrict__ invd4_3, float* __restrict__ Ctot)
{
    float s = 0.f;
    for (int i = blockIdx.x * 256 + threadIdx.x; i < 3 * NN * 4; i += gridDim.x * 256)
        s += invd4_3[i];
#pragma unroll
    for (int off = 32; off; off >>= 1) s += __shfl_down(s, off);
    if ((threadIdx.x & 63) == 0) atomicAdd(Ctot, s);
}

// ------------------------------------------------------------------
// gather (FUSED edge weights): one block per (node, head).
// Phase A: compute this head's edge weights once, LDS stash, denom
//   reduce -> iv (plain invd4 store), write w*iv to wpkl (for
//   importance), rescale stash to w*iv.
// Phase B: pair-load row gather using w*iv; v = csum*iv + acc.
// Whb head-major [h][N][256] (2 MB/XCD working set). No atomics.
// ------------------------------------------------------------------
__global__ __launch_bounds__(256)
void gather_kernel(const unsigned short* __restrict__ Whb,
                   const float* __restrict__ es, const float* __restrict__ ed,
                   const int* __restrict__ rowptr, const int* __restrict__ cdst,
                   const float* __restrict__ csum,
                   float* __restrict__ wpkl,     // [4][EE] this layer, w*iv
                   float* __restrict__ invd4,    // [NN*4] this layer
                   unsigned short* __restrict__ hb_out,
                   const float* __restrict__ pwp, float* __restrict__ ps4)
{
    __shared__ float wlds[MAXDEG];
    __shared__ float red[4][DH];
    __shared__ float swred[4];
    const int b = blockIdx.x;
    const int xcd = b & 7;
    const int h = xcd >> 1;
    const int n = (b >> 3) + (xcd & 1) * (NN / 2);
    const int tid = threadIdx.x;
    const int w = tid >> 6, lane = tid & 63;
    const int beg = rowptr[n], end = rowptr[n + 1];
    const int deg = end - beg;
    const float esh = es[n * 4 + h];

    // ---- Phase A: this head's edge weights ----
    float sw = 0.f;
    for (int i = tid; i < deg; i += 256) {
        int d = cdst[beg + i];
        float v = esh + ed[d * 4 + h];
        v = v > 0.f ? v : ALPHA_LR * v;
        float wv = expm1f(v);
        sw += wv;
        if (i < MAXDEG) wlds[i] = wv;
    }
#pragma unroll
    for (int off = 32; off; off >>= 1) sw += __shfl_xor(sw, off);
    if (lane == 0) swred[w] = sw;
    __syncthreads();
    const float iv = 1.f / ((float)NN + swred[0] + swred[1] + swred[2] + swred[3]);
    if (tid == 0) invd4[n * 4 + h] = iv;
    for (int i = tid; i < deg; i += 256) {
        float wv;
        if (i < MAXDEG) wv = wlds[i];
        else {
            int d = cdst[beg + i];
            float v = esh + ed[d * 4 + h];
            v = v > 0.f ? v : ALPHA_LR * v;
            wv = expm1f(v);
        }
        float wiv = wv * iv;
        wpkl[beg + i] = wiv;
        if (i < MAXDEG) wlds[i] = wiv;
    }
    __syncthreads();

    // ---- Phase B: pair-load row gather (weights = w*iv) ----
    const int slot = lane >> 5;
    const int c8 = (lane & 31) * 8;
    const unsigned short* basep = Whb + (size_t)h * NN * DH + c8;
    float acc[8] = {};
    for (int i0 = w * 8; i0 < deg; i0 += 32) {
        float ww[4]; int dd[4];
#pragma unroll
        for (int p = 0; p < 4; ++p) {
            int e = i0 + p * 2 + slot;
            int ec = e < deg ? e : (deg - 1);
            dd[p] = cdst[beg + ec];
            if (e < deg) {
                if (e < MAXDEG) ww[p] = wlds[e];
                else {
                    float v = esh + ed[dd[p] * 4 + h];
                    v = v > 0.f ? v : ALPHA_LR * v;
                    ww[p] = expm1f(v) * iv;
                }
            } else ww[p] = 0.f;
        }
        short8 vv[4];
#pragma unroll
        for (int p = 0; p < 4; ++p)
            vv[p] = *(const short8*)(basep + (size_t)dd[p] * DH);
#pragma unroll
        for (int p = 0; p < 4; ++p)
#pragma unroll
            for (int j = 0; j < 8; ++j)
                acc[j] = fmaf(ww[p], bf2f((unsigned short)vv[p][j]), acc[j]);
    }
#pragma unroll
    for (int j = 0; j < 8; ++j) acc[j] += __shfl_xor(acc[j], 32);
    if (lane < 32) {
        *(f32x4*)(&red[w][c8])     = (f32x4){acc[0], acc[1], acc[2], acc[3]};
        *(f32x4*)(&red[w][c8 + 4]) = (f32x4){acc[4], acc[5], acc[6], acc[7]};
    }
    __syncthreads();

    // wave-0 epilogue: 4 cols/lane, vectorized
    if (tid < 64) {
        f32x4 s0 = *(const f32x4*)(&red[0][tid * 4]);
        f32x4 s1 = *(const f32x4*)(&red[1][tid * 4]);
        f32x4 s2 = *(const f32x4*)(&red[2][tid * 4]);
        f32x4 s3 = *(const f32x4*)(&red[3][tid * 4]);
        f32x4 cs = *(const f32x4*)(&csum[h * DH + tid * 4]);
        f32x4 r;
        s16x4 ob;
#pragma unroll
        for (int j = 0; j < 4; ++j) {
            float v = cs[j] * iv + s0[j] + s1[j] + s2[j] + s3[j];
            v = v > 0.f ? v : expm1f(v);
            r[j] = v;
            ob[j] = (short)f2bf(v);
        }
        *(s16x4*)(&hb_out[(size_t)n * DCAT + h * DH + tid * 4]) = ob;
        if (pwp) {
            f32x4 pv = *(const f32x4*)(&pwp[h * DH + tid * 4]);
            float p = r[0] * pv[0] + r[1] * pv[1] + r[2] * pv[2] + r[3] * pv[3];
#pragma unroll
            for (int off = 32; off; off >>= 1) p += __shfl_down(p, off);
            if (tid == 0) ps4[n * 4 + h] = p;
        }
    }
}

// ------------------------------------------------------------------
// importance gather over incoming edges (CSC) + natt output.
// wpk3 = [12][EE] of w*iv (3 layers x 4 heads); 16 lanes per node.
// ------------------------------------------------------------------
__global__ void impgather_kernel(const int* __restrict__ cscptr, const int* __restrict__ cscpos,
                                 const float* __restrict__ wpk3, const float* __restrict__ Ctot,
                                 float* __restrict__ out)
{
    int gid = blockIdx.x * 256 + threadIdx.x;
    int m = gid >> 4;
    int l = gid & 15;
    int beg = cscptr[m], end = cscptr[m + 1];
    float s = 0.f;
    for (int j = beg + l; j < end; j += 16) {
        int p = cscpos[j];
        float t = 0.f;
#pragma unroll
        for (int q = 0; q < 12; ++q) t += wpk3[(size_t)q * EE + p];
        s += t;
    }
    s += __shfl_down(s, 8, 16);
    s += __shfl_down(s, 4, 16);
    s += __shfl_down(s, 2, 16);
    s += __shfl_down(s, 1, 16);
    if (l == 0) out[7 + m] = (s + Ctot[0]) * (1.0f / 12.0f);
}

// ------------------------------------------------------------------
// emb with fused node-softmax over ps4; 4 outputs/thread via s16x4.
// grid (1, 16)
// ------------------------------------------------------------------
__global__ void emb_kernel(const unsigned short* __restrict__ h3, const float* __restrict__ ps4,
                           float* __restrict__ emb)
{
    __shared__ float red[8];
    __shared__ float MM, SS;
    __shared__ float pawl[256];
    int t = threadIdx.x;
    float m = -1e30f;
    for (int i = t; i < NN; i += 256) {
        f32x4 q = *(const f32x4*)(ps4 + i * 4);
        m = fmaxf(m, q[0] + q[1] + q[2] + q[3]);
    }
#pragma unroll
    for (int off = 32; off; off >>= 1) m = fmaxf(m, __shfl_down(m, off));
    if ((t & 63) == 0) red[t >> 6] = m;
    __syncthreads();
    if (t == 0) MM = fmaxf(fmaxf(red[0], red[1]), fmaxf(red[2], red[3]));
    __syncthreads();
    float s = 0.f;
    for (int i = t; i < NN; i += 256) {
        f32x4 q = *(const f32x4*)(ps4 + i * 4);
        s += expf(q[0] + q[1] + q[2] + q[3] - MM);
    }
#pragma unroll
    for (int off = 32; off; off >>= 1) s += __shfl_down(s, off);
    __syncthreads();
    if ((t & 63) == 0) red[t >> 6] = s;
    __syncthreads();
    if (t == 0) SS = red[0] + red[1] + red[2] + red[3];
    __syncthreads();
    int n0 = blockIdx.y * 256;
    {
        f32x4 q = *(const f32x4*)(ps4 + (n0 + t) * 4);
        pawl[t] = expf(q[0] + q[1] + q[2] + q[3] - MM) / SS;
    }
    __syncthreads();
    float a0 = 0.f, a1 = 0.f, a2 = 0.f, a3 = 0.f;
    for (int j = 0; j < 256; ++j) {
        float pw = pawl[j];
        s16x4 v = *(const s16x4*)(&h3[(size_t)(n0 + j) * DCAT + t * 4]);
        a0 = fmaf(pw, bf2f((unsigned short)v[0]), a0);
        a1 = fmaf(pw, bf2f((unsigned short)v[1]), a1);
        a2 = fmaf(pw, bf2f((unsigned short)v[2]), a2);
        a3 = fmaf(pw, bf2f((unsigned short)v[3]), a3);
    }
    atomicAdd(&emb[t * 4 + 0], a0);
    atomicAdd(&emb[t * 4 + 1], a1);
    atomicAdd(&emb[t * 4 + 2], a2);
    atomicAdd(&emb[t * 4 + 3], a3);
}

__global__ void c1_kernel(const float* __restrict__ emb, const float* __restrict__ c1w,
                          float* __restrict__ zbuf)
{
    int t = threadIdx.x;
    int r0 = blockIdx.x * 32;
    float s = 0.f;
#pragma unroll
    for (int j = 0; j < 32; ++j)
        s = fmaf(emb[r0 + j], c1w[(size_t)(r0 + j) * DH + t], s);
    atomicAdd(&zbuf[t], s);
}

__global__ void c2_kernel(const float* __restrict__ zbuf, const float* __restrict__ c1b,
                          const float* __restrict__ c2w, const float* __restrict__ c2b,
                          float* __restrict__ out)
{
    __shared__ float z[DH];
    __shared__ float lgs[8];
    int t = threadIdx.x;
    z[t] = fmaxf(zbuf[t] + c1b[t], 0.f);
    __syncthreads();
    int g = t >> 5, k = t & 31;
    if (g < 7) {
        float s = 0.f;
#pragma unroll
        for (int j = 0; j < 8; ++j)
            s = fmaf(z[k + 32 * j], c2w[(k + 32 * j) * 7 + g], s);
#pragma unroll
        for (int off = 16; off; off >>= 1) s += __shfl_down(s, off, 32);
        if (k == 0) lgs[g] = s + c2b[g];
    }
    __syncthreads();
    if (t == 0) {
        float m = lgs[0];
        for (int i = 1; i < 7; ++i) m = fmaxf(m, lgs[i]);
        float sm = 0.f, ex[7];
        for (int i = 0; i < 7; ++i) { ex[i] = expf(lgs[i] - m); sm += ex[i]; }
        for (int i = 0; i < 7; ++i) out[i] = ex[i] / sm;
    }
}

// ------------------------------------------------------------------
extern "C" void kernel_launch(void* const* d_in, const int* in_sizes, int n_in,
                              void* d_out, int out_size, void* d_ws, size_t ws_size,
                              hipStream_t stream)
{
    const float* x   = (const float*)d_in[0];
    const int*   ei  = (const int*)d_in[1];
    const float* Wp  = (const float*)d_in[2];
    const float* bp  = (const float*)d_in[3];
    const float* W[3]  = {(const float*)d_in[4], (const float*)d_in[6], (const float*)d_in[8]};
    const float* av[3] = {(const float*)d_in[5], (const float*)d_in[7], (const float*)d_in[9]};
    const float* pw  = (const float*)d_in[10];
    const float* c1w = (const float*)d_in[12];
    const float* c1b = (const float*)d_in[13];
    const float* c2w = (const float*)d_in[14];
    const float* c2b = (const float*)d_in[15];
    float* out = (float*)d_out;
    (void)in_sizes; (void)n_in; (void)out_size; (void)ws_size;

    char* base = (char*)d_ws;
    size_t off = 0;
    auto alloc = [&](size_t bytes) -> void* {
        void* p = base + off;
        off = (off + bytes + 255) & ~(size_t)255;
        return p;
    };
    // ---- zero region (single memset) ----
    size_t zero_begin = off;
    float* es4_3 = (float*)alloc((size_t)3 * NN * 16);
    float* ed4_3 = (float*)alloc((size_t)3 * NN * 16);
    float* csum3 = (float*)alloc((size_t)3 * DCAT * 4);
    float* Ctot  = (float*)alloc(256);
    int*   counts  = (int*)alloc(NN * 4);
    int*   counts2 = (int*)alloc(NN * 4);
    float* emb   = (float*)alloc(DCAT * 4);
    float* zbuf  = (float*)alloc(DH * 4);
    size_t zero_bytes = off - zero_begin;
    // ---- rest ----
    unsigned short* xb   = (unsigned short*)alloc((size_t)NN * DIN * 2);
    unsigned short* BTp  = (unsigned short*)alloc((size_t)DH * DIN * 2);
    unsigned short* BT0  = (unsigned short*)alloc((size_t)DCAT * DH * 2);
    unsigned short* BT1  = (unsigned short*)alloc((size_t)DCAT * DCAT * 2);
    unsigned short* BT2  = (unsigned short*)alloc((size_t)DCAT * DCAT * 2);
    unsigned short* Whb  = (unsigned short*)alloc((size_t)NN * DCAT * 2);   // head-major [4][N][256]
    unsigned short* hb0  = (unsigned short*)alloc((size_t)NN * DCAT * 2);
    unsigned short* hb1  = (unsigned short*)alloc((size_t)NN * DCAT * 2);
    int*   rowptr  = (int*)alloc((NN + 1) * 4);
    int*   cursor  = (int*)alloc(NN * 4);
    int*   cscptr  = (int*)alloc((NN + 1) * 4);
    int*   ccursor = (int*)alloc(NN * 4);
    int*   cdst    = (int*)alloc((size_t)EE * 4);
    int*   cscpos  = (int*)alloc((size_t)EE * 4);
    float* wpk3    = (float*)alloc((size_t)3 * HH * EE * 4);   // [layer][head][EE], w*iv
    float* invd4_3 = (float*)alloc((size_t)3 * NN * 16);
    float* ps4     = (float*)alloc((size_t)NN * 16);

    const int* srcp = ei;
    const int* dstp = ei + EE;

    hipMemsetAsync(base + zero_begin, 0, zero_bytes, stream);

    // merged prep: cast + transposes + edge counts
    prep_kernel<<<3360, 256, 0, stream>>>(x, xb, Wp, BTp, W[0], BT0, W[1], BT1, W[2], BT2,
                                          srcp, dstp, counts, counts2);
    scan2_kernel<<<1, 1024, 0, stream>>>(counts, counts2, rowptr, cursor, cscptr, ccursor);
    fill_kernel<<<EE / 256, 256, 0, stream>>>(srcp, dstp, cursor, ccursor, cdst, cscpos);

    // projection: hb0[N][256] = relu(x @ Wp + bp)   (node-major)
    mfma_gemm_kernel<<<dim3(NN / 128, DH / 128), 256, 0, stream>>>(
        xb, BTp, DIN, hb0, DH, 0, bp, 1, nullptr, nullptr, nullptr, nullptr);

    unsigned short* cur = hb0;
    unsigned short* nxt = hb1;
    const unsigned short* BTl[3] = {BT0, BT1, BT2};
    for (int layer = 0; layer < 3; ++layer) {
        int K = (layer == 0) ? DH : DCAT;
        float* es = es4_3 + (size_t)layer * NN * 4;
        float* ed = ed4_3 + (size_t)layer * NN * 4;
        float* csum = csum3 + (size_t)layer * DCAT;
        float* wpkl = wpk3 + (size_t)layer * HH * EE;
        float* invd4 = invd4_3 + (size_t)layer * NN * 4;
        mfma_gemm_kernel<<<dim3(NN / 128, DCAT / 128), 256, 0, stream>>>(
            cur, BTl[layer], K, Whb, DCAT, 1, nullptr, 0, av[layer], es, ed, csum);
        gather_kernel<<<NN * HH, 256, 0, stream>>>(Whb, es, ed, rowptr, cdst, csum,
                                                   wpkl, invd4, nxt,
                                                   (layer == 2) ? pw : nullptr, ps4);
        unsigned short* t = cur; cur = nxt; nxt = t;
    }

    // Ctot from invd4_3 (few atomics)
    ctot_reduce_kernel<<<24, 256, 0, stream>>>(invd4_3, Ctot);

    // pooling (softmax fused into emb) + classifier on bf16 h3 (cur)
    emb_kernel<<<dim3(1, 16), 256, 0, stream>>>(cur, ps4, emb);
    c1_kernel<<<32, 256, 0, stream>>>(emb, c1w, zbuf);
    c2_kernel<<<1, 256, 0, stream>>>(zbuf, c1b, c2w, c2b, out);

    // importance (atomic-free CSC gather over 12 wpk arrays) + natt output
    impgather_kernel<<<NN * 16 / 256, 256, 0, stream>>>(cscptr, cscpos, wpk3, Ctot, out);
}

// Round 15
// 279.661 us; speedup vs baseline: 1.0805x; 1.0805x over previous
//
#include <hip/hip_runtime.h>
#include <hip/hip_bf16.h>
#include <math.h>

#define NN   4096
#define EE   131072
#define HH   4
#define DIN  128
#define DH   256
#define DCAT 1024   /* HH*DH */
#define ALPHA_LR 0.2f

typedef __attribute__((ext_vector_type(8))) short  short8;
typedef __attribute__((ext_vector_type(4))) short  s16x4;
typedef __attribute__((ext_vector_type(4))) float  f32x4;

__device__ __forceinline__ unsigned short f2bf(float f) {
    union { float f; unsigned u; } v; v.f = f;
    unsigned r = v.u + 0x7fffu + ((v.u >> 16) & 1u);
    return (unsigned short)(r >> 16);
}
__device__ __forceinline__ float bf2f(unsigned short us) {
    union { unsigned u; float f; } v; v.u = ((unsigned)us) << 16;
    return v.f;
}

// ------------------------------------------------------------------
// merged prep: cast x -> bf16 | 4 weight transposes | edge counts
// ------------------------------------------------------------------
__global__ void prep_kernel(const float* __restrict__ x, unsigned short* __restrict__ xb,
                            const float* __restrict__ Wp, unsigned short* __restrict__ BTp,
                            const float* __restrict__ W0, unsigned short* __restrict__ BT0,
                            const float* __restrict__ W1, unsigned short* __restrict__ BT1,
                            const float* __restrict__ W2, unsigned short* __restrict__ BT2,
                            const int* __restrict__ src, const int* __restrict__ dst,
                            int* __restrict__ counts, int* __restrict__ counts2)
{
    __shared__ float tile[32][33];
    const int b = blockIdx.x, tid = threadIdx.x;
    if (b < 512) {                               // cast x
        int i = b * 256 + tid;
        f32x4 v = *(const f32x4*)(x + (size_t)i * 4);
        s16x4 o;
        o[0] = (short)f2bf(v[0]); o[1] = (short)f2bf(v[1]);
        o[2] = (short)f2bf(v[2]); o[3] = (short)f2bf(v[3]);
        *(s16x4*)(xb + (size_t)i * 4) = o;
        return;
    }
    if (b >= 2848) {                             // edge degree counts
        int e = (b - 2848) * 256 + tid;
        atomicAdd(&counts[src[e]], 1);
        atomicAdd(&counts2[dst[e]], 1);
        return;
    }
    const float* W; unsigned short* BT; int K, h, kt, ot;
    if (b < 544)       { int c = b - 512;  W = Wp; BT = BTp; K = DIN;  h = 0;      kt = c & 3;  ot = c >> 2; }
    else if (b < 800)  { int c = b - 544;  W = W0; BT = BT0; K = DH;   h = c >> 6; kt = c & 7;  ot = (c >> 3) & 7; }
    else if (b < 1824) { int c = b - 800;  W = W1; BT = BT1; K = DCAT; h = c >> 8; kt = c & 31; ot = (c >> 5) & 7; }
    else               { int c = b - 1824; W = W2; BT = BT2; K = DCAT; h = c >> 8; kt = c & 31; ot = (c >> 5) & 7; }
    int k0 = kt * 32, o0 = ot * 32;
    int tx = tid & 31, ty = tid >> 5;
    const float* Ws = W + (size_t)h * K * 256;
#pragma unroll
    for (int i = 0; i < 32; i += 8)
        tile[ty + i][tx] = Ws[(size_t)(k0 + ty + i) * 256 + o0 + tx];
    __syncthreads();
#pragma unroll
    for (int i = 0; i < 32; i += 8)
        BT[(size_t)(h * 256 + o0 + ty + i) * K + k0 + tx] = f2bf(tile[tx][ty + i]);
}

// ------------------------------------------------------------------
// bf16 MFMA GEMM; head_major writes C as [h][N][256] (for Whb).
// Fused es/ed/csum epilogue when av != null.
// ------------------------------------------------------------------
__global__ __launch_bounds__(256)
void mfma_gemm_kernel(const unsigned short* __restrict__ A,
                      const unsigned short* __restrict__ BT,
                      int K,
                      unsigned short* __restrict__ Cb,
                      int ldc, int head_major,
                      const float* __restrict__ bias, int relu_act,
                      const float* __restrict__ av,
                      float* __restrict__ es4, float* __restrict__ ed4,
                      float* __restrict__ csum)
{
    __shared__ __align__(16) unsigned short sA[2][128 * 32];
    __shared__ __align__(16) unsigned short sB[2][128 * 32];

    const int tid = threadIdx.x;
    const int w = tid >> 6, l = tid & 63;
    const int wr = w >> 1, wc = w & 1;
    const int row0 = blockIdx.x * 128, col0 = blockIdx.y * 128;
    const int lrow = l >> 2;
    const int lce  = (l & 3) * 8;
    const int lr = l & 15, lg = l >> 4;

    f32x4 acc[4][4];
#pragma unroll
    for (int m = 0; m < 4; ++m)
#pragma unroll
        for (int n = 0; n < 4; ++n)
            acc[m][n] = (f32x4){0.f, 0.f, 0.f, 0.f};

#define STAGE(buf, k0)                                                          \
    {                                                                           \
        _Pragma("unroll")                                                       \
        for (int p = 0; p < 2; ++p) {                                           \
            int chunk = w * 2 + p;                                              \
            int r = chunk * 16 + lrow;                                          \
            const unsigned short* ga = A  + (size_t)(row0 + r) * K + (k0) + lce;\
            const unsigned short* gb = BT + (size_t)(col0 + r) * K + (k0) + lce;\
            __builtin_amdgcn_global_load_lds(                                   \
                (const __attribute__((address_space(1))) unsigned int*)ga,      \
                (__attribute__((address_space(3))) unsigned int*)(&sA[buf][chunk * 512]), \
                16, 0, 0);                                                      \
            __builtin_amdgcn_global_load_lds(                                   \
                (const __attribute__((address_space(1))) unsigned int*)gb,      \
                (__attribute__((address_space(3))) unsigned int*)(&sB[buf][chunk * 512]), \
                16, 0, 0);                                                      \
        }                                                                       \
    }

#define COMPUTE(buf)                                                            \
    {                                                                           \
        short8 af[4], bfr[4];                                                   \
        _Pragma("unroll")                                                       \
        for (int m = 0; m < 4; ++m) {                                           \
            int r = wr * 64 + m * 16 + lr;                                      \
            af[m] = *(const short8*)(&sA[buf][r * 32 + lg * 8]);                \
        }                                                                       \
        _Pragma("unroll")                                                       \
        for (int n = 0; n < 4; ++n) {                                           \
            int r = wc * 64 + n * 16 + lr;                                      \
            bfr[n] = *(const short8*)(&sB[buf][r * 32 + lg * 8]);               \
        }                                                                       \
        _Pragma("unroll")                                                       \
        for (int m = 0; m < 4; ++m)                                             \
            _Pragma("unroll")                                                   \
            for (int n = 0; n < 4; ++n)                                         \
                acc[m][n] = __builtin_amdgcn_mfma_f32_16x16x32_bf16(            \
                    af[m], bfr[n], acc[m][n], 0, 0, 0);                         \
    }

    STAGE(0, 0);
    __syncthreads();
    int nt = K >> 5, cur = 0;
    for (int t = 0; t < nt - 1; ++t) {
        STAGE(cur ^ 1, (t + 1) * 32);
        COMPUTE(cur);
        __syncthreads();
        cur ^= 1;
    }
    COMPUTE(cur);
#undef STAGE
#undef COMPUTE

    // C-write
#pragma unroll
    for (int m = 0; m < 4; ++m) {
        int rbase = row0 + wr * 64 + m * 16 + lg * 4;
#pragma unroll
        for (int n = 0; n < 4; ++n) {
            int c = col0 + wc * 64 + n * 16 + lr;
            float bv = bias ? bias[c] : 0.f;
#pragma unroll
            for (int r = 0; r < 4; ++r) {
                float v = acc[m][n][r] + bv;
                if (relu_act) v = fmaxf(v, 0.f);
                size_t idx = head_major
                    ? (size_t)(c >> 8) * ((size_t)NN * DH) + (size_t)(rbase + r) * DH + (c & 255)
                    : (size_t)(rbase + r) * ldc + c;
                Cb[idx] = f2bf(v);
            }
        }
    }

    // fused attvec + colsum epilogue
    if (av) {
        const int h = (col0 + wc * 64) >> 8;
        float aes[4], aed[4];
#pragma unroll
        for (int n = 0; n < 4; ++n) {
            int cc = (col0 + wc * 64 + n * 16 + lr) & 255;
            aes[n] = av[h * 2 * DH + cc];
            aed[n] = av[h * 2 * DH + DH + cc];
        }
#pragma unroll
        for (int m = 0; m < 4; ++m) {
#pragma unroll
            for (int r = 0; r < 4; ++r) {
                float se = 0.f, sd = 0.f;
#pragma unroll
                for (int n = 0; n < 4; ++n) {
                    se = fmaf(aes[n], acc[m][n][r], se);
                    sd = fmaf(aed[n], acc[m][n][r], sd);
                }
                se += __shfl_xor(se, 1);  sd += __shfl_xor(sd, 1);
                se += __shfl_xor(se, 2);  sd += __shfl_xor(sd, 2);
                se += __shfl_xor(se, 4);  sd += __shfl_xor(sd, 4);
                se += __shfl_xor(se, 8);  sd += __shfl_xor(sd, 8);
                if (lr == 0) {
                    int row = row0 + wr * 64 + m * 16 + lg * 4 + r;
                    atomicAdd(&es4[row * 4 + h], se);
                    atomicAdd(&ed4[row * 4 + h], sd);
                }
            }
        }
#pragma unroll
        for (int n = 0; n < 4; ++n) {
            float s = 0.f;
#pragma unroll
            for (int m = 0; m < 4; ++m)
#pragma unroll
                for (int r = 0; r < 4; ++r)
                    s += acc[m][n][r];
            s += __shfl_xor(s, 16);
            s += __shfl_xor(s, 32);
            if (lg == 0) atomicAdd(&csum[col0 + wc * 64 + n * 16 + lr], s);
        }
    }
}

// ------------------------------------------------------------------
// dual scan + fill (CSR/CSC)
// ------------------------------------------------------------------
__global__ void scan2_kernel(const int* __restrict__ countsA, const int* __restrict__ countsB,
                             int* __restrict__ rowptr, int* __restrict__ cursor,
                             int* __restrict__ cscptr, int* __restrict__ ccursor)
{
    __shared__ int lsumA[1024];
    __shared__ int lsumB[1024];
    int t = threadIdx.x;
    int base = t * 4;
    int a0 = countsA[base], a1 = countsA[base + 1], a2 = countsA[base + 2], a3 = countsA[base + 3];
    int b0 = countsB[base], b1 = countsB[base + 1], b2 = countsB[base + 2], b3 = countsB[base + 3];
    int sA = a0 + a1 + a2 + a3;
    int sB = b0 + b1 + b2 + b3;
    lsumA[t] = sA; lsumB[t] = sB;
    __syncthreads();
    for (int off = 1; off < 1024; off <<= 1) {
        int vA = (t >= off) ? lsumA[t - off] : 0;
        int vB = (t >= off) ? lsumB[t - off] : 0;
        __syncthreads();
        lsumA[t] += vA; lsumB[t] += vB;
        __syncthreads();
    }
    int eA = lsumA[t] - sA;
    rowptr[base] = eA;               cursor[base] = eA;
    rowptr[base + 1] = eA + a0;      cursor[base + 1] = eA + a0;
    rowptr[base + 2] = eA + a0 + a1; cursor[base + 2] = eA + a0 + a1;
    rowptr[base + 3] = eA + a0 + a1 + a2; cursor[base + 3] = eA + a0 + a1 + a2;
    int eB = lsumB[t] - sB;
    cscptr[base] = eB;               ccursor[base] = eB;
    cscptr[base + 1] = eB + b0;      ccursor[base + 1] = eB + b0;
    cscptr[base + 2] = eB + b0 + b1; ccursor[base + 2] = eB + b0 + b1;
    cscptr[base + 3] = eB + b0 + b1 + b2; ccursor[base + 3] = eB + b0 + b1 + b2;
    if (t == 1023) { rowptr[NN] = lsumA[1023]; cscptr[NN] = lsumB[1023]; }
}

__global__ void fill_kernel(const int* __restrict__ src, const int* __restrict__ dst,
                            int* __restrict__ cursor, int* __restrict__ ccursor,
                            int* __restrict__ cdst, int* __restrict__ cscpos)
{
    int e = blockIdx.x * 256 + threadIdx.x;
    int s = src[e], d = dst[e];
    int pos = atomicAdd(&cursor[s], 1);
    cdst[pos] = d;
    int cp = atomicAdd(&ccursor[d], 1);
    cscpos[cp] = pos;
}

// ------------------------------------------------------------------
// edgew: one WAVE per node (4 nodes/block). NO atomics.
// ------------------------------------------------------------------
__global__ __launch_bounds__(256)
void edgew_kernel(const float* __restrict__ es, const float* __restrict__ ed,
                  const int* __restrict__ rowptr, const int* __restrict__ cdst,
                  float* __restrict__ wpk,      // [4][EE]
                  float* __restrict__ invd4,    // [NN][4] (this layer)
                  float* __restrict__ wi)
{
    const int wave = threadIdx.x >> 6, lane = threadIdx.x & 63;
    const int n = blockIdx.x * 4 + wave;
    const int beg = rowptr[n], end = rowptr[n + 1];
    const int deg = end - beg;
    const float es0 = es[n * 4 + 0], es1 = es[n * 4 + 1];
    const float es2 = es[n * 4 + 2], es3 = es[n * 4 + 3];

    float sw0 = 0.f, sw1 = 0.f, sw2 = 0.f, sw3 = 0.f;
    for (int i = lane; i < deg; i += 64) {
        int d = cdst[beg + i];
        f32x4 ev = *(const f32x4*)(ed + d * 4);
        float v0 = es0 + ev[0]; v0 = v0 > 0.f ? v0 : ALPHA_LR * v0;
        float v1 = es1 + ev[1]; v1 = v1 > 0.f ? v1 : ALPHA_LR * v1;
        float v2 = es2 + ev[2]; v2 = v2 > 0.f ? v2 : ALPHA_LR * v2;
        float v3 = es3 + ev[3]; v3 = v3 > 0.f ? v3 : ALPHA_LR * v3;
        float w0 = expm1f(v0), w1 = expm1f(v1), w2 = expm1f(v2), w3 = expm1f(v3);
        sw0 += w0; sw1 += w1; sw2 += w2; sw3 += w3;
        wpk[beg + i] = w0;
        wpk[EE + beg + i] = w1;
        wpk[2 * EE + beg + i] = w2;
        wpk[3 * EE + beg + i] = w3;
    }
#pragma unroll
    for (int off = 32; off; off >>= 1) {
        sw0 += __shfl_xor(sw0, off);
        sw1 += __shfl_xor(sw1, off);
        sw2 += __shfl_xor(sw2, off);
        sw3 += __shfl_xor(sw3, off);
    }
    const float iv0 = 1.f / ((float)NN + sw0);
    const float iv1 = 1.f / ((float)NN + sw1);
    const float iv2 = 1.f / ((float)NN + sw2);
    const float iv3 = 1.f / ((float)NN + sw3);
    if (lane == 0)
        *(f32x4*)(invd4 + n * 4) = (f32x4){iv0, iv1, iv2, iv3};
    for (int i = lane; i < deg; i += 64) {
        float w0 = wpk[beg + i], w1 = wpk[EE + beg + i];
        float w2 = wpk[2 * EE + beg + i], w3 = wpk[3 * EE + beg + i];
        wi[beg + i] = fmaf(w0, iv0, fmaf(w1, iv1, fmaf(w2, iv2, w3 * iv3)));
    }
}

// ------------------------------------------------------------------
// Ctot = sum of invd4_3 (few atomics)
// ------------------------------------------------------------------
__global__ void ctot_reduce_kernel(const float* __restrict__ invd4_3, float* __restrict__ Ctot)
{
    float s = 0.f;
    for (int i = blockIdx.x * 256 + threadIdx.x; i < 3 * NN * 4; i += gridDim.x * 256)
        s += invd4_3[i];
#pragma unroll
    for (int off = 32; off; off >>= 1) s += __shfl_down(s, off);
    if ((threadIdx.x & 63) == 0) atomicAdd(Ctot, s);
}

// ------------------------------------------------------------------
// gather: one block per (node, head); Whb head-major [h][N][256] so
// each XCD's working set is 2 MB. Pair-loads: each wave iteration
// fetches TWO rows (lane halves = edge slots, short8 16B/lane).
// Wave-0-only vectorized epilogue. No per-edge atomics.
// ------------------------------------------------------------------
__global__ __launch_bounds__(256)
void gather_kernel(const unsigned short* __restrict__ Whb,
                   const float* __restrict__ wpk, const int* __restrict__ rowptr,
                   const int* __restrict__ cdst, const float* __restrict__ invd4,
                   const float* __restrict__ csum,
                   unsigned short* __restrict__ hb_out,
                   const float* __restrict__ pwp, float* __restrict__ ps4)
{
    __shared__ float red[4][DH];
    const int b = blockIdx.x;
    const int xcd = b & 7;
    const int h = xcd >> 1;
    const int n = (b >> 3) + (xcd & 1) * (NN / 2);
    const int tid = threadIdx.x;
    const int w = tid >> 6, lane = tid & 63;
    const int slot = lane >> 5;             // which edge of a pair
    const int c8 = (lane & 31) * 8;         // 8-col group
    const int beg = rowptr[n], end = rowptr[n + 1];
    const int deg = end - beg;
    const float* wph = wpk + (size_t)h * EE;
    const unsigned short* basep = Whb + (size_t)h * NN * DH + c8;

    float acc[8] = {};
    for (int i0 = w * 8; i0 < deg; i0 += 32) {
        float ww[4]; int dd[4];
#pragma unroll
        for (int p = 0; p < 4; ++p) {
            int e = i0 + p * 2 + slot;
            int ec = e < deg ? e : (deg - 1);
            ww[p] = (e < deg) ? wph[beg + ec] : 0.f;
            dd[p] = cdst[beg + ec];
        }
        short8 vv[4];
#pragma unroll
        for (int p = 0; p < 4; ++p)
            vv[p] = *(const short8*)(basep + (size_t)dd[p] * DH);
#pragma unroll
        for (int p = 0; p < 4; ++p)
#pragma unroll
            for (int j = 0; j < 8; ++j)
                acc[j] = fmaf(ww[p], bf2f((unsigned short)vv[p][j]), acc[j]);
    }
    // combine the two edge slots
#pragma unroll
    for (int j = 0; j < 8; ++j) acc[j] += __shfl_xor(acc[j], 32);
    if (lane < 32) {
        *(f32x4*)(&red[w][c8])     = (f32x4){acc[0], acc[1], acc[2], acc[3]};
        *(f32x4*)(&red[w][c8 + 4]) = (f32x4){acc[4], acc[5], acc[6], acc[7]};
    }
    __syncthreads();

    // wave-0 epilogue: 4 cols/lane, vectorized
    if (tid < 64) {
        const float iv = invd4[n * 4 + h];
        f32x4 s0 = *(const f32x4*)(&red[0][tid * 4]);
        f32x4 s1 = *(const f32x4*)(&red[1][tid * 4]);
        f32x4 s2 = *(const f32x4*)(&red[2][tid * 4]);
        f32x4 s3 = *(const f32x4*)(&red[3][tid * 4]);
        f32x4 cs = *(const f32x4*)(&csum[h * DH + tid * 4]);
        f32x4 r;
        s16x4 ob;
#pragma unroll
        for (int j = 0; j < 4; ++j) {
            float v = (cs[j] + s0[j] + s1[j] + s2[j] + s3[j]) * iv;
            v = v > 0.f ? v : expm1f(v);
            r[j] = v;
            ob[j] = (short)f2bf(v);
        }
        *(s16x4*)(&hb_out[(size_t)n * DCAT + h * DH + tid * 4]) = ob;
        if (pwp) {
            f32x4 pv = *(const f32x4*)(&pwp[h * DH + tid * 4]);
            float p = r[0] * pv[0] + r[1] * pv[1] + r[2] * pv[2] + r[3] * pv[3];
#pragma unroll
            for (int off = 32; off; off >>= 1) p += __shfl_down(p, off);
            if (tid == 0) ps4[n * 4 + h] = p;
        }
    }
}

// ------------------------------------------------------------------
// importance gather over incoming edges (CSC) + natt output.
// ------------------------------------------------------------------
__global__ void impgather_kernel(const int* __restrict__ cscptr, const int* __restrict__ cscpos,
                                 const float* __restrict__ wi0, const float* __restrict__ wi1,
                                 const float* __restrict__ wi2, const float* __restrict__ Ctot,
                                 float* __restrict__ out)
{
    int gid = blockIdx.x * 256 + threadIdx.x;
    int m = gid >> 3;
    int l = gid & 7;
    int beg = cscptr[m], end = cscptr[m + 1];
    float s = 0.f;
    for (int j = beg + l; j < end; j += 8) {
        int p = cscpos[j];
        s += wi0[p] + wi1[p] + wi2[p];
    }
    s += __shfl_down(s, 4, 8);
    s += __shfl_down(s, 2, 8);
    s += __shfl_down(s, 1, 8);
    if (l == 0) out[7 + m] = (s + Ctot[0]) * (1.0f / 12.0f);
}

// ------------------------------------------------------------------
// emb with fused node-softmax over ps4; 4 outputs/thread via s16x4.
// grid (1, 16)
// ------------------------------------------------------------------
__global__ void emb_kernel(const unsigned short* __restrict__ h3, const float* __restrict__ ps4,
                           float* __restrict__ emb)
{
    __shared__ float red[8];
    __shared__ float MM, SS;
    __shared__ float pawl[256];
    int t = threadIdx.x;
    float m = -1e30f;
    for (int i = t; i < NN; i += 256) {
        f32x4 q = *(const f32x4*)(ps4 + i * 4);
        m = fmaxf(m, q[0] + q[1] + q[2] + q[3]);
    }
#pragma unroll
    for (int off = 32; off; off >>= 1) m = fmaxf(m, __shfl_down(m, off));
    if ((t & 63) == 0) red[t >> 6] = m;
    __syncthreads();
    if (t == 0) MM = fmaxf(fmaxf(red[0], red[1]), fmaxf(red[2], red[3]));
    __syncthreads();
    float s = 0.f;
    for (int i = t; i < NN; i += 256) {
        f32x4 q = *(const f32x4*)(ps4 + i * 4);
        s += expf(q[0] + q[1] + q[2] + q[3] - MM);
    }
#pragma unroll
    for (int off = 32; off; off >>= 1) s += __shfl_down(s, off);
    __syncthreads();
    if ((t & 63) == 0) red[t >> 6] = s;
    __syncthreads();
    if (t == 0) SS = red[0] + red[1] + red[2] + red[3];
    __syncthreads();
    int n0 = blockIdx.y * 256;
    {
        f32x4 q = *(const f32x4*)(ps4 + (n0 + t) * 4);
        pawl[t] = expf(q[0] + q[1] + q[2] + q[3] - MM) / SS;
    }
    __syncthreads();
    float a0 = 0.f, a1 = 0.f, a2 = 0.f, a3 = 0.f;
    for (int j = 0; j < 256; ++j) {
        float pw = pawl[j];
        s16x4 v = *(const s16x4*)(&h3[(size_t)(n0 + j) * DCAT + t * 4]);
        a0 = fmaf(pw, bf2f((unsigned short)v[0]), a0);
        a1 = fmaf(pw, bf2f((unsigned short)v[1]), a1);
        a2 = fmaf(pw, bf2f((unsigned short)v[2]), a2);
        a3 = fmaf(pw, bf2f((unsigned short)v[3]), a3);
    }
    atomicAdd(&emb[t * 4 + 0], a0);
    atomicAdd(&emb[t * 4 + 1], a1);
    atomicAdd(&emb[t * 4 + 2], a2);
    atomicAdd(&emb[t * 4 + 3], a3);
}

__global__ void c1_kernel(const float* __restrict__ emb, const float* __restrict__ c1w,
                          float* __restrict__ zbuf)
{
    int t = threadIdx.x;
    int r0 = blockIdx.x * 32;
    float s = 0.f;
#pragma unroll
    for (int j = 0; j < 32; ++j)
        s = fmaf(emb[r0 + j], c1w[(size_t)(r0 + j) * DH + t], s);
    atomicAdd(&zbuf[t], s);
}

__global__ void c2_kernel(const float* __restrict__ zbuf, const float* __restrict__ c1b,
                          const float* __restrict__ c2w, const float* __restrict__ c2b,
                          float* __restrict__ out)
{
    __shared__ float z[DH];
    __shared__ float lgs[8];
    int t = threadIdx.x;
    z[t] = fmaxf(zbuf[t] + c1b[t], 0.f);
    __syncthreads();
    int g = t >> 5, k = t & 31;
    if (g < 7) {
        float s = 0.f;
#pragma unroll
        for (int j = 0; j < 8; ++j)
            s = fmaf(z[k + 32 * j], c2w[(k + 32 * j) * 7 + g], s);
#pragma unroll
        for (int off = 16; off; off >>= 1) s += __shfl_down(s, off, 32);
        if (k == 0) lgs[g] = s + c2b[g];
    }
    __syncthreads();
    if (t == 0) {
        float m = lgs[0];
        for (int i = 1; i < 7; ++i) m = fmaxf(m, lgs[i]);
        float sm = 0.f, ex[7];
        for (int i = 0; i < 7; ++i) { ex[i] = expf(lgs[i] - m); sm += ex[i]; }
        for (int i = 0; i < 7; ++i) out[i] = ex[i] / sm;
    }
}

// ------------------------------------------------------------------
extern "C" void kernel_launch(void* const* d_in, const int* in_sizes, int n_in,
                              void* d_out, int out_size, void* d_ws, size_t ws_size,
                              hipStream_t stream)
{
    const float* x   = (const float*)d_in[0];
    const int*   ei  = (const int*)d_in[1];
    const float* Wp  = (const float*)d_in[2];
    const float* bp  = (const float*)d_in[3];
    const float* W[3]  = {(const float*)d_in[4], (const float*)d_in[6], (const float*)d_in[8]};
    const float* av[3] = {(const float*)d_in[5], (const float*)d_in[7], (const float*)d_in[9]};
    const float* pw  = (const float*)d_in[10];
    const float* c1w = (const float*)d_in[12];
    const float* c1b = (const float*)d_in[13];
    const float* c2w = (const float*)d_in[14];
    const float* c2b = (const float*)d_in[15];
    float* out = (float*)d_out;
    (void)in_sizes; (void)n_in; (void)out_size; (void)ws_size;

    char* base = (char*)d_ws;
    size_t off = 0;
    auto alloc = [&](size_t bytes) -> void* {
        void* p = base + off;
        off = (off + bytes + 255) & ~(size_t)255;
        return p;
    };
    // ---- zero region (single memset) ----
    size_t zero_begin = off;
    float* es4_3 = (float*)alloc((size_t)3 * NN * 16);
    float* ed4_3 = (float*)alloc((size_t)3 * NN * 16);
    float* csum3 = (float*)alloc((size_t)3 * DCAT * 4);
    float* Ctot  = (float*)alloc(256);
    int*   counts  = (int*)alloc(NN * 4);
    int*   counts2 = (int*)alloc(NN * 4);
    float* emb   = (float*)alloc(DCAT * 4);
    float* zbuf  = (float*)alloc(DH * 4);
    size_t zero_bytes = off - zero_begin;
    // ---- rest ----
    unsigned short* xb   = (unsigned short*)alloc((size_t)NN * DIN * 2);
    unsigned short* BTp  = (unsigned short*)alloc((size_t)DH * DIN * 2);
    unsigned short* BT0  = (unsigned short*)alloc((size_t)DCAT * DH * 2);
    unsigned short* BT1  = (unsigned short*)alloc((size_t)DCAT * DCAT * 2);
    unsigned short* BT2  = (unsigned short*)alloc((size_t)DCAT * DCAT * 2);
    unsigned short* Whb  = (unsigned short*)alloc((size_t)NN * DCAT * 2);   // head-major [4][N][256]
    unsigned short* hb0  = (unsigned short*)alloc((size_t)NN * DCAT * 2);
    unsigned short* hb1  = (unsigned short*)alloc((size_t)NN * DCAT * 2);
    int*   rowptr  = (int*)alloc((NN + 1) * 4);
    int*   cursor  = (int*)alloc(NN * 4);
    int*   cscptr  = (int*)alloc((NN + 1) * 4);
    int*   ccursor = (int*)alloc(NN * 4);
    int*   cdst    = (int*)alloc((size_t)EE * 4);
    int*   cscpos  = (int*)alloc((size_t)EE * 4);
    float* wi3     = (float*)alloc((size_t)3 * EE * 4);
    float* wpk     = (float*)alloc((size_t)HH * EE * 4);
    float* invd4_3 = (float*)alloc((size_t)3 * NN * 16);
    float* ps4     = (float*)alloc((size_t)NN * 16);

    const int* srcp = ei;
    const int* dstp = ei + EE;

    hipMemsetAsync(base + zero_begin, 0, zero_bytes, stream);

    // merged prep: cast + transposes + edge counts
    prep_kernel<<<3360, 256, 0, stream>>>(x, xb, Wp, BTp, W[0], BT0, W[1], BT1, W[2], BT2,
                                          srcp, dstp, counts, counts2);
    scan2_kernel<<<1, 1024, 0, stream>>>(counts, counts2, rowptr, cursor, cscptr, ccursor);
    fill_kernel<<<EE / 256, 256, 0, stream>>>(srcp, dstp, cursor, ccursor, cdst, cscpos);

    // projection: hb0[N][256] = relu(x @ Wp + bp)   (node-major)
    mfma_gemm_kernel<<<dim3(NN / 128, DH / 128), 256, 0, stream>>>(
        xb, BTp, DIN, hb0, DH, 0, bp, 1, nullptr, nullptr, nullptr, nullptr);

    unsigned short* cur = hb0;
    unsigned short* nxt = hb1;
    const unsigned short* BTl[3] = {BT0, BT1, BT2};
    for (int layer = 0; layer < 3; ++layer) {
        int K = (layer == 0) ? DH : DCAT;
        float* es = es4_3 + (size_t)layer * NN * 4;
        float* ed = ed4_3 + (size_t)layer * NN * 4;
        float* csum = csum3 + (size_t)layer * DCAT;
        float* wi = wi3 + (size_t)layer * EE;
        float* invd4 = invd4_3 + (size_t)layer * NN * 4;
        mfma_gemm_kernel<<<dim3(NN / 128, DCAT / 128), 256, 0, stream>>>(
            cur, BTl[layer], K, Whb, DCAT, 1, nullptr, 0, av[layer], es, ed, csum);
        edgew_kernel<<<NN / 4, 256, 0, stream>>>(es, ed, rowptr, cdst, wpk, invd4, wi);
        gather_kernel<<<NN * HH, 256, 0, stream>>>(Whb, wpk, rowptr, cdst, invd4, csum, nxt,
                                                   (layer == 2) ? pw : nullptr, ps4);
        unsigned short* t = cur; cur = nxt; nxt = t;
    }

    // Ctot from invd4_3 (few atomics)
    ctot_reduce_kernel<<<24, 256, 0, stream>>>(invd4_3, Ctot);

    // pooling (softmax fused into emb) + classifier on bf16 h3 (cur)
    emb_kernel<<<dim3(1, 16), 256, 0, stream>>>(cur, ps4, emb);
    c1_kernel<<<32, 256, 0, stream>>>(emb, c1w, zbuf);
    c2_kernel<<<1, 256, 0, stream>>>(zbuf, c1b, c2w, c2b, out);

    // importance (atomic-free CSC gather) + node_attention output
    impgather_kernel<<<NN * 8 / 256, 256, 0, stream>>>(cscptr, cscpos,
        wi3, wi3 + EE, wi3 + 2 * EE, Ctot, out);
}